// Round 4
// baseline (86.778 us; speedup 1.0000x reference)
//
#include <hip/hip_runtime.h>

#define N_P 256
#define N_T 32
#define OFFDIAG 65280       // 256*255
#define QROWS 1024          // 32*32
#define QBLOCKS (QROWS * 64)  // 64 blocks per quality row, one float4/thread
#define TAILBLKS 255          // 255*256 = 65280

// Exact reference fp order: inter / ((area_a + area_b) - inter)
__device__ __forceinline__ float iou_one(float a0, float a1, float a2, float a3,
                                         float ta,
                                         float b0, float b1, float b2, float b3,
                                         float areaB) {
    float lt0 = fmaxf(a0, b0), lt1 = fmaxf(a1, b1);
    float rb0 = fminf(a2, b2), rb1 = fminf(a3, b3);
    float w = fmaxf((rb0 - lt0) + 1.0f, 0.0f);
    float h = fmaxf((rb1 - lt1) + 1.0f, 0.0f);
    float inter = w * h;
    return inter / ((ta + areaB) - inter);
}

// ---------------------------------------------------------------------------
// Single fused kernel, no inter-block dependencies.
//   blocks [0, QBLOCKS): quality rows. Each block computes its two iou rows
//     inline from pb/tb (prefolded by 0.5), then stores 256 float4 = 4KB of
//     one quality row. Same store structure as the round-1 56µs version.
//   blocks [QBLOCKS, QBLOCKS+TAILBLKS): matched/labels/box+idx pairs. Each
//     thread recomputes per-proposal best (max+first-argmax over 32 targets)
//     for its i and j — bit-identical fp sequence via iou_one.
// ---------------------------------------------------------------------------
__global__ void relpn_fused_kernel(const float* __restrict__ pb,
                                   const float* __restrict__ tb,
                                   const int* __restrict__ tpl,
                                   float* __restrict__ out) {
    int tid = threadIdx.x;
    unsigned blk = blockIdx.x;

    if (blk < QBLOCKS) {
        // ---------------- quality path ----------------
        unsigned pq = blk >> 6;          // [0, 1024)
        unsigned seg = blk & 63u;        // 64 segments of 1024 elements
        int p = pq >> 5, q = pq & 31;

        __shared__ float rp[N_P], rq[N_P];
        // uniform (scalar) target-box loads
        float pa0 = tb[p * 4 + 0], pa1 = tb[p * 4 + 1];
        float pa2 = tb[p * 4 + 2], pa3 = tb[p * 4 + 3];
        float pta = ((pa2 - pa0) + 1.0f) * ((pa3 - pa1) + 1.0f);
        float qa0 = tb[q * 4 + 0], qa1 = tb[q * 4 + 1];
        float qa2 = tb[q * 4 + 2], qa3 = tb[q * 4 + 3];
        float qta = ((qa2 - qa0) + 1.0f) * ((qa3 - qa1) + 1.0f);

        float4 B = reinterpret_cast<const float4*>(pb)[tid];
        float areaB = ((B.z - B.x) + 1.0f) * ((B.w - B.y) + 1.0f);
        // prefold 0.5: 0.5a + 0.5b is bit-identical to 0.5*(a+b)
        rp[tid] = 0.5f * iou_one(pa0, pa1, pa2, pa3, pta, B.x, B.y, B.z, B.w, areaB);
        rq[tid] = 0.5f * iou_one(qa0, qa1, qa2, qa3, qta, B.x, B.y, B.z, B.w, areaB);
        __syncthreads();

        int f = (int)seg * 256 + tid;    // float4 index within row
        if (f * 4 < OFFDIAG) {
            int k = f * 4;
            int i = (unsigned)k / 255u;
            int r = k - i * 255;
            float4 v;
            float* vv = reinterpret_cast<float*>(&v);
            #pragma unroll
            for (int e = 0; e < 4; ++e) {
                if (r >= 255) { r -= 255; ++i; }
                int j = r + (r >= i ? 1 : 0);
                vv[e] = rp[i] + rq[j];
                ++r;
            }
            reinterpret_cast<float4*>(out + (size_t)pq * OFFDIAG)[f] = v;
        }
    } else {
        // ---------------- tail path ----------------
        int k = (int)(blk - QBLOCKS) * 256 + tid;     // [0, 65280)
        float* matched = out + (size_t)QROWS * OFFDIAG;
        float* labels  = matched + OFFDIAG;
        float* pbp     = labels + OFFDIAG;
        float* pip     = pbp + (size_t)OFFDIAG * 8;
        float* tbp     = pip + (size_t)OFFDIAG * 2;

        int i = (unsigned)k / 255u;
        int r = k - i * 255;
        int j = r + (r >= i ? 1 : 0);

        float4 Bi = reinterpret_cast<const float4*>(pb)[i];
        float4 Bj = reinterpret_cast<const float4*>(pb)[j];
        float areaBi = ((Bi.z - Bi.x) + 1.0f) * ((Bi.w - Bi.y) + 1.0f);
        float areaBj = ((Bj.z - Bj.x) + 1.0f) * ((Bj.w - Bj.y) + 1.0f);

        float bvi = -1.0f, bvj = -1.0f;
        int bii = 0, bij = 0;
        #pragma unroll
        for (int t = 0; t < N_T; ++t) {
            // uniform scalar loads of target box t
            float a0 = tb[t * 4 + 0], a1 = tb[t * 4 + 1];
            float a2 = tb[t * 4 + 2], a3 = tb[t * 4 + 3];
            float ta = ((a2 - a0) + 1.0f) * ((a3 - a1) + 1.0f);
            float vi = iou_one(a0, a1, a2, a3, ta, Bi.x, Bi.y, Bi.z, Bi.w, areaBi);
            float vj = iou_one(a0, a1, a2, a3, ta, Bj.x, Bj.y, Bj.z, Bj.w, areaBj);
            if (vi > bvi) { bvi = vi; bii = t; }      // strict > == first occurrence
            if (vj > bvj) { bvj = vj; bij = t; }
        }

        float mv = 0.5f * (bvi + bvj);
        int mi, lab;
        if (mv < 0.3f)      { mi = -1; lab = 0; }
        else if (mv < 0.5f) { mi = -2; lab = -1; }
        else                { mi = bii * N_T + bij; lab = tpl[mi]; }

        matched[k] = (float)mi;
        labels[k]  = (float)lab;

        reinterpret_cast<float4*>(pbp)[k * 2 + 0] = Bi;
        reinterpret_cast<float4*>(pbp)[k * 2 + 1] = Bj;
        pip[k * 2 + 0] = (float)i;
        pip[k * 2 + 1] = (float)j;

        if (k < QROWS) {
            int pp = k >> 5, qq = k & 31;
            reinterpret_cast<float4*>(tbp)[k * 2 + 0] =
                reinterpret_cast<const float4*>(tb)[pp];
            reinterpret_cast<float4*>(tbp)[k * 2 + 1] =
                reinterpret_cast<const float4*>(tb)[qq];
        }
    }
}

extern "C" void kernel_launch(void* const* d_in, const int* in_sizes, int n_in,
                              void* d_out, int out_size, void* d_ws, size_t ws_size,
                              hipStream_t stream) {
    const float* pb  = (const float*)d_in[0];   // proposal_boxes [256,4]
    const float* tb  = (const float*)d_in[1];   // target_boxes   [32,4]
    const int*   tpl = (const int*)d_in[2];     // target_pair_labels [1024]
    float* out = (float*)d_out;

    relpn_fused_kernel<<<QBLOCKS + TAILBLKS, 256, 0, stream>>>(pb, tb, tpl, out);
}

// Round 5
// 52.898 us; speedup vs baseline: 1.6405x; 1.6405x over previous
//
#include <hip/hip_runtime.h>

#define N_P 256
#define N_T 32
#define OFFDIAG 65280   // 256*255
#define QROWS 1024      // 32*32

// ---------------------------------------------------------------------------
// Kernel 1: iou[32][256] in exact reference fp order + per-proposal best
// (max over 32 targets, first-occurrence argmax).  [unchanged from R1]
// ---------------------------------------------------------------------------
__global__ void iou_best_kernel(const float* __restrict__ pb,
                                const float* __restrict__ tb,
                                float* __restrict__ iou,
                                float* __restrict__ bv,
                                int* __restrict__ bidx) {
    __shared__ float t0[N_T], t1[N_T], t2[N_T], t3[N_T], ta[N_T];
    int tid = threadIdx.x;
    if (tid < N_T) {
        float a0 = tb[tid * 4 + 0], a1 = tb[tid * 4 + 1];
        float a2 = tb[tid * 4 + 2], a3 = tb[tid * 4 + 3];
        t0[tid] = a0; t1[tid] = a1; t2[tid] = a2; t3[tid] = a3;
        ta[tid] = ((a2 - a0) + 1.0f) * ((a3 - a1) + 1.0f);   // area_a, ref order
    }
    __syncthreads();
    int p = tid;
    float b0 = pb[p * 4 + 0], b1 = pb[p * 4 + 1];
    float b2 = pb[p * 4 + 2], b3 = pb[p * 4 + 3];
    float areaB = ((b2 - b0) + 1.0f) * ((b3 - b1) + 1.0f);
    float bestv = -1.0f;
    int besti = 0;
    #pragma unroll
    for (int t = 0; t < N_T; ++t) {
        float lt0 = fmaxf(t0[t], b0), lt1 = fmaxf(t1[t], b1);
        float rb0 = fminf(t2[t], b2), rb1 = fminf(t3[t], b3);
        float w = fmaxf((rb0 - lt0) + 1.0f, 0.0f);
        float h = fmaxf((rb1 - lt1) + 1.0f, 0.0f);
        float inter = w * h;
        float v = inter / ((ta[t] + areaB) - inter);  // ref op order
        iou[t * N_P + p] = v;
        if (v > bestv) { bestv = v; besti = t; }      // strict > == first occurrence
    }
    bv[p] = bestv;
    bidx[p] = besti;
}

// ---------------------------------------------------------------------------
// Kernel 2: quality [1024 x 65280]. One block per row; each WAVE owns
// i-segments (i = wave + 4n). rp[i] is wave-uniform (SGPR via readfirstlane),
// rq[j] reads are stride-1 (bank-conflict-free), stores are 64-contiguous
// scalar dwords streamed back-to-back. 0.5 prefolded at staging (bit-exact:
// *0.5 is exact scaling, commutes with rounding).
// Row layout: segment i covers cols [i*255, i*255+255): value = rp[i]+rq[j],
// j = pos + (pos>=i)  (diagonal skip).
// ---------------------------------------------------------------------------
__global__ void quality_kernel(const float* __restrict__ iou,
                               float* __restrict__ qout) {
    int pq = blockIdx.x;
    int p = pq >> 5, q = pq & 31;
    __shared__ float rp[N_P], rq[N_P];
    int tid = threadIdx.x;
    rp[tid] = 0.5f * iou[p * N_P + tid];
    rq[tid] = 0.5f * iou[q * N_P + tid];
    __syncthreads();

    int wave = tid >> 6, lane = tid & 63;
    float* dst = qout + (size_t)pq * OFFDIAG;

    for (int i0 = wave; i0 < N_P; i0 += 4) {
        int i = __builtin_amdgcn_readfirstlane(i0);   // wave-uniform -> SGPR
        float a = rp[i];                              // LDS broadcast
        int ibase = i * 255;
        #pragma unroll
        for (int m = 0; m < 4; ++m) {
            int pos = m * 64 + lane;
            if (pos < 255) {                          // only m==3 masks (lane 63)
                int j = pos + (pos >= i ? 1 : 0);
                dst[ibase + pos] = a + rq[j];
            }
        }
    }
}

// ---------------------------------------------------------------------------
// Kernel 3: matched_idxs, labels, box/idx pairs.  [unchanged from R1]
// ---------------------------------------------------------------------------
__global__ void tail_kernel(const float* __restrict__ pb,
                            const float* __restrict__ tb,
                            const int* __restrict__ tpl,
                            const float* __restrict__ bv,
                            const int* __restrict__ bidx,
                            float* __restrict__ out) {
    int k = blockIdx.x * 256 + threadIdx.x;           // [0, 65280)
    float* matched = out + (size_t)QROWS * OFFDIAG;
    float* labels  = matched + OFFDIAG;
    float* pbp     = labels + OFFDIAG;
    float* pip     = pbp + (size_t)OFFDIAG * 8;
    float* tbp     = pip + (size_t)OFFDIAG * 2;

    int i = (unsigned)k / 255u;
    int r = k - i * 255;
    int j = r + (r >= i ? 1 : 0);

    float mv = 0.5f * (bv[i] + bv[j]);
    int mi, lab;
    if (mv < 0.3f)      { mi = -1; lab = 0; }
    else if (mv < 0.5f) { mi = -2; lab = -1; }
    else                { mi = bidx[i] * N_T + bidx[j]; lab = tpl[mi]; }

    matched[k] = (float)mi;
    labels[k]  = (float)lab;

    float4 bi = reinterpret_cast<const float4*>(pb)[i];
    float4 bj = reinterpret_cast<const float4*>(pb)[j];
    reinterpret_cast<float4*>(pbp)[k * 2 + 0] = bi;
    reinterpret_cast<float4*>(pbp)[k * 2 + 1] = bj;
    pip[k * 2 + 0] = (float)i;
    pip[k * 2 + 1] = (float)j;

    if (k < QROWS) {
        int pp = k >> 5, qq = k & 31;
        reinterpret_cast<float4*>(tbp)[k * 2 + 0] =
            reinterpret_cast<const float4*>(tb)[pp];
        reinterpret_cast<float4*>(tbp)[k * 2 + 1] =
            reinterpret_cast<const float4*>(tb)[qq];
    }
}

extern "C" void kernel_launch(void* const* d_in, const int* in_sizes, int n_in,
                              void* d_out, int out_size, void* d_ws, size_t ws_size,
                              hipStream_t stream) {
    const float* pb  = (const float*)d_in[0];   // proposal_boxes [256,4]
    const float* tb  = (const float*)d_in[1];   // target_boxes   [32,4]
    const int*   tpl = (const int*)d_in[2];     // target_pair_labels [1024]
    float* out = (float*)d_out;

    float* iou  = (float*)d_ws;                 // 32*256 f32 = 32 KB
    float* bv   = iou + N_T * N_P;              // 256 f32
    int*   bidx = (int*)(bv + N_P);             // 256 i32

    iou_best_kernel<<<1, 256, 0, stream>>>(pb, tb, iou, bv, bidx);
    quality_kernel<<<QROWS, 256, 0, stream>>>(iou, out);
    tail_kernel<<<OFFDIAG / 256, 256, 0, stream>>>(pb, tb, tpl, bv, bidx, out);
}